// Round 2
// baseline (773.106 us; speedup 1.0000x reference)
//
#include <hip/hip_runtime.h>
#include <hip/hip_bf16.h>

// Problem constants
constexpr int Nn  = 20000;
constexpr int Ee  = 320000;
constexpr int Hh  = 6;
constexpr int Cc  = 64;
constexpr int HC  = 384;   // Hh*Cc
constexpr int Gg  = 64;
constexpr int NF  = 6;
constexpr int EP  = Ee + Nn;  // edges incl self-loops

// ---------------- workspace layout (bytes) ----------------
constexpr size_t OFF_H1   = 0;                              // N*HC f32 (reused as h2)
constexpr size_t OFF_X2   = OFF_H1  + (size_t)Nn*HC*4;      // N*HC f32
constexpr size_t OFF_AS1  = OFF_X2  + (size_t)Nn*HC*4;      // N*H
constexpr size_t OFF_AD1  = OFF_AS1 + (size_t)Nn*Hh*4;
constexpr size_t OFF_AS2  = OFF_AD1 + (size_t)Nn*Hh*4;
constexpr size_t OFF_AD2  = OFF_AS2 + (size_t)Nn*Hh*4;
constexpr size_t OFF_OFFS = OFF_AD2 + (size_t)Nn*Hh*4;      // (N+1) int
constexpr size_t OFF_ESRC = OFF_OFFS + ((size_t)(Nn+1)*4 + 255 & ~(size_t)255);
constexpr size_t OFF_EEA  = OFF_ESRC + (size_t)EP*4;
constexpr size_t OFF_W2T  = OFF_EEA  + (size_t)EP*4;        // 384*384 f32
// ---- zeroed block (single memset) ----
constexpr size_t OFF_ZERO = OFF_W2T + (size_t)HC*HC*4;
constexpr size_t OFF_CNT  = OFF_ZERO;                       // N int
constexpr size_t OFF_CNT2 = OFF_CNT  + (size_t)Nn*4;        // N int
constexpr size_t OFF_CNTG = OFF_CNT2 + (size_t)Nn*4;        // G int
constexpr size_t OFF_POOL = OFF_CNTG + (size_t)Gg*4;        // G*HC f32
constexpr size_t OFF_SCAL = OFF_POOL + (size_t)Gg*HC*4;     // 64 f32: [0]=sum_ea, [1..6]=wedot1, [7..12]=wedot2
constexpr size_t ZERO_BYTES = OFF_SCAL + 64*4 - OFF_ZERO;

__device__ __forceinline__ float wave_red64(float v) {
    #pragma unroll
    for (int o = 32; o; o >>= 1) v += __shfl_down(v, o);
    return v;
}

// -------- mean of edge_attr (sum; divided later) --------
__global__ void k_mean(const float* __restrict__ ea, float* __restrict__ scal) {
    int i = blockIdx.x * blockDim.x + threadIdx.x;
    float v = 0.f;
    for (int j = i; j < Ee; j += gridDim.x * blockDim.x) v += ea[j];
    v = wave_red64(v);
    if ((threadIdx.x & 63) == 0) atomicAdd(&scal[0], v);
}

// -------- we_dot[h] = sum_c We[h*64+c]*atte[h*64+c], both layers --------
__global__ void k_wedot(const float* __restrict__ we1, const float* __restrict__ atte1,
                        const float* __restrict__ we2, const float* __restrict__ atte2,
                        float* __restrict__ scal) {
    int t = threadIdx.x;  // 384
    float p1 = we1[t] * atte1[t];
    float p2 = we2[t] * atte2[t];
    p1 = wave_red64(p1);
    p2 = wave_red64(p2);
    if ((t & 63) == 0) { int h = t >> 6; scal[1 + h] = p1; scal[7 + h] = p2; }
}

// -------- h1 = x @ W1^T, plus attention dots --------
__global__ __launch_bounds__(HC) void k_h1(const float* __restrict__ x, const float* __restrict__ w1,
                                           const float* __restrict__ asrc, const float* __restrict__ adst,
                                           float* __restrict__ h1, float* __restrict__ as_, float* __restrict__ ad_) {
    int n = blockIdx.x, t = threadIdx.x;
    float acc = 0.f;
    #pragma unroll
    for (int k = 0; k < NF; k++) acc += x[n * NF + k] * w1[t * NF + k];
    h1[(size_t)n * HC + t] = acc;
    float s = acc * asrc[t], d = acc * adst[t];
    s = wave_red64(s);
    d = wave_red64(d);
    if ((t & 63) == 0) { int h = t >> 6; as_[n * Hh + h] = s; ad_[n * Hh + h] = d; }
}

// -------- CSR build --------
__global__ void k_count(const int* __restrict__ dst, int* __restrict__ cnt) {
    int i = blockIdx.x * blockDim.x + threadIdx.x;
    if (i < EP) {
        int d = (i < Ee) ? dst[i] : (i - Ee);
        atomicAdd(&cnt[d], 1);
    }
}

__global__ void k_scan(const int* __restrict__ cnt, int* __restrict__ offs) {
    __shared__ int lds[1024];
    __shared__ int carry;
    int t = threadIdx.x;
    if (t == 0) carry = 0;
    __syncthreads();
    for (int base = 0; base < Nn; base += 1024) {
        int v = (base + t < Nn) ? cnt[base + t] : 0;
        lds[t] = v;
        __syncthreads();
        for (int o = 1; o < 1024; o <<= 1) {
            int tv = (t >= o) ? lds[t - o] : 0;
            __syncthreads();
            lds[t] += tv;
            __syncthreads();
        }
        if (base + t < Nn) offs[base + t] = carry + lds[t] - v;  // exclusive
        __syncthreads();
        if (t == 1023) carry += lds[1023];
        __syncthreads();
    }
    if (t == 0) offs[Nn] = carry;
}

__global__ void k_scatter(const int* __restrict__ src, const int* __restrict__ dst,
                          const float* __restrict__ ea, const int* __restrict__ offs,
                          int* __restrict__ cnt2, int* __restrict__ esrc, float* __restrict__ eea,
                          const float* __restrict__ scal) {
    int i = blockIdx.x * blockDim.x + threadIdx.x;
    if (i >= EP) return;
    int d, s; float a;
    if (i < Ee) { d = dst[i]; s = src[i]; a = ea[i]; }
    else        { d = i - Ee; s = d; a = scal[0] * (1.0f / Ee); }
    int p = offs[d] + atomicAdd(&cnt2[d], 1);
    esrc[p] = s;
    eea[p]  = a;
}

// -------- aggregation: per dst node online-softmax + weighted sum --------
template <int LAYER>
__global__ __launch_bounds__(HC) void k_agg(const float* __restrict__ hin, const float* __restrict__ as_,
                                            const float* __restrict__ ad_, const int* __restrict__ offs,
                                            const int* __restrict__ esrc, const float* __restrict__ eea,
                                            const float* __restrict__ scal, const float* __restrict__ bias,
                                            const int* __restrict__ batch,
                                            float* __restrict__ outx, float* __restrict__ pool) {
    int n = blockIdx.x, t = threadIdx.x, h = t >> 6;
    int s0 = offs[n], s1 = offs[n + 1];
    float adn = ad_[n * Hh + h];
    float wdh = scal[(LAYER == 1 ? 1 : 7) + h];
    float m = -3.4e38f, den = 0.f, acc = 0.f;
    for (int j = s0; j < s1; ++j) {
        int s   = esrc[j];
        float a = eea[j];
        float al = as_[s * Hh + h] + adn + a * wdh;
        al = (al > 0.f) ? al : 0.2f * al;                 // leaky_relu 0.2
        float mn   = fmaxf(m, al);
        float corr = __expf(m - mn);
        float p    = __expf(al - mn);
        den = den * corr + p;
        acc = acc * corr + p * hin[(size_t)s * HC + t];
        m = mn;
    }
    float o = acc / den + bias[t];
    float e = (o > 0.f) ? o : (__expf(o) - 1.f);          // ELU
    if (LAYER == 1) {
        outx[(size_t)n * HC + t] = e;
    } else {
        atomicAdd(&pool[batch[n] * HC + t], e);
    }
}

// -------- transpose W2 --------
__global__ void k_tr(const float* __restrict__ w2, float* __restrict__ w2t) {
    int i = blockIdx.x * blockDim.x + threadIdx.x;
    if (i < HC * HC) {
        int j = i / HC, k = i % HC;
        w2t[k * HC + j] = w2[i];
    }
}

// -------- GEMM: h2 = x2 @ W2^T  ([N,384] x [384,384]) --------
constexpr int NPB = 16;
__global__ __launch_bounds__(HC) void k_gemm(const float* __restrict__ x2, const float* __restrict__ w2t,
                                             float* __restrict__ h2) {
    __shared__ float xs[NPB * HC];
    int t = threadIdx.x;
    int n0 = blockIdx.x * NPB;
    #pragma unroll
    for (int i = 0; i < NPB; i++) {
        int n = n0 + i;
        xs[i * HC + t] = (n < Nn) ? x2[(size_t)n * HC + t] : 0.f;
    }
    __syncthreads();
    float acc[NPB];
    #pragma unroll
    for (int i = 0; i < NPB; i++) acc[i] = 0.f;
    for (int k = 0; k < HC; k++) {
        float w = w2t[k * HC + t];
        #pragma unroll
        for (int i = 0; i < NPB; i++) acc[i] += xs[i * HC + k] * w;
    }
    #pragma unroll
    for (int i = 0; i < NPB; i++) {
        int n = n0 + i;
        if (n < Nn) h2[(size_t)n * HC + t] = acc[i];
    }
}

// -------- attention dots for layer 2 --------
__global__ __launch_bounds__(HC) void k_attn2(const float* __restrict__ h2, const float* __restrict__ asrc,
                                              const float* __restrict__ adst,
                                              float* __restrict__ as_, float* __restrict__ ad_) {
    int n = blockIdx.x, t = threadIdx.x;
    float v = h2[(size_t)n * HC + t];
    float s = v * asrc[t], d = v * adst[t];
    s = wave_red64(s);
    d = wave_red64(d);
    if ((t & 63) == 0) { int h = t >> 6; as_[n * Hh + h] = s; ad_[n * Hh + h] = d; }
}

__global__ void k_cntg(const int* __restrict__ batch, int* __restrict__ cntg) {
    int i = blockIdx.x * blockDim.x + threadIdx.x;
    if (i < Nn) atomicAdd(&cntg[batch[i]], 1);
}

// -------- final: per-graph mean pool -> linear -> sigmoid --------
__global__ __launch_bounds__(HC) void k_final(const float* __restrict__ pool, const int* __restrict__ cntg,
                                              const float* __restrict__ wlin, float* __restrict__ out) {
    __shared__ float partial[Hh];
    int g = blockIdx.x, t = threadIdx.x;
    float v = pool[g * HC + t] * wlin[t];
    v = wave_red64(v);
    if ((t & 63) == 0) partial[t >> 6] = v;
    __syncthreads();
    if (t == 0) {
        float s = 0.f;
        #pragma unroll
        for (int h = 0; h < Hh; h++) s += partial[h];
        int c = cntg[g];
        float denom = (float)(c > 1 ? c : 1);
        float logit = s / denom;
        out[g] = 1.f / (1.f + __expf(-logit));
    }
}

extern "C" void kernel_launch(void* const* d_in, const int* in_sizes, int n_in,
                              void* d_out, int out_size, void* d_ws, size_t ws_size,
                              hipStream_t stream) {
    const float* x        = (const float*)d_in[0];
    const float* ea       = (const float*)d_in[1];
    const int*   eidx     = (const int*)d_in[2];   // [2,E]: src row then dst row
    const int*   batch    = (const int*)d_in[3];
    const float* w1       = (const float*)d_in[4];
    const float* att_src1 = (const float*)d_in[5];
    const float* att_dst1 = (const float*)d_in[6];
    const float* we1      = (const float*)d_in[7];
    const float* atte1    = (const float*)d_in[8];
    const float* b1       = (const float*)d_in[9];
    const float* w2       = (const float*)d_in[10];
    const float* att_src2 = (const float*)d_in[11];
    const float* att_dst2 = (const float*)d_in[12];
    const float* we2      = (const float*)d_in[13];
    const float* atte2    = (const float*)d_in[14];
    const float* b2       = (const float*)d_in[15];
    const float* wlin     = (const float*)d_in[16];
    float* out = (float*)d_out;

    char* ws = (char*)d_ws;
    float* h1   = (float*)(ws + OFF_H1);
    float* x2   = (float*)(ws + OFF_X2);
    float* h2   = h1;                          // reuse: h1 dead after agg1
    float* as1  = (float*)(ws + OFF_AS1);
    float* ad1  = (float*)(ws + OFF_AD1);
    float* as2  = (float*)(ws + OFF_AS2);
    float* ad2  = (float*)(ws + OFF_AD2);
    int*   offs = (int*)(ws + OFF_OFFS);
    int*   esrc = (int*)(ws + OFF_ESRC);
    float* eea  = (float*)(ws + OFF_EEA);
    float* w2t  = (float*)(ws + OFF_W2T);
    int*   cnt  = (int*)(ws + OFF_CNT);
    int*   cnt2 = (int*)(ws + OFF_CNT2);
    int*   cntg = (int*)(ws + OFF_CNTG);
    float* pool = (float*)(ws + OFF_POOL);
    float* scal = (float*)(ws + OFF_SCAL);

    const int* src = eidx;
    const int* dst = eidx + Ee;

    // zero the accumulator block
    hipMemsetAsync(ws + OFF_ZERO, 0, ZERO_BYTES, stream);

    // scalars
    k_mean<<<256, 256, 0, stream>>>(ea, scal);
    k_wedot<<<1, HC, 0, stream>>>(we1, atte1, we2, atte2, scal);

    // layer-1 projection + attention dots
    k_h1<<<Nn, HC, 0, stream>>>(x, w1, att_src1, att_dst1, h1, as1, ad1);

    // CSR build
    int ecb = (EP + 255) / 256;
    k_count<<<ecb, 256, 0, stream>>>(dst, cnt);
    k_scan<<<1, 1024, 0, stream>>>(cnt, offs);
    k_scatter<<<ecb, 256, 0, stream>>>(src, dst, ea, offs, cnt2, esrc, eea, scal);

    // layer-1 aggregation -> x2 (with ELU)
    k_agg<1><<<Nn, HC, 0, stream>>>(h1, as1, ad1, offs, esrc, eea, scal, b1, nullptr, x2, nullptr);

    // layer-2 projection
    k_tr<<<(HC * HC + 255) / 256, 256, 0, stream>>>(w2, w2t);
    k_gemm<<<(Nn + NPB - 1) / NPB, HC, 0, stream>>>(x2, w2t, h2);
    k_attn2<<<Nn, HC, 0, stream>>>(h2, att_src2, att_dst2, as2, ad2);

    // pooling counts
    k_cntg<<<(Nn + 255) / 256, 256, 0, stream>>>(batch, cntg);

    // layer-2 aggregation -> pool (with ELU)
    k_agg<2><<<Nn, HC, 0, stream>>>(h2, as2, ad2, offs, esrc, eea, scal, b2, batch, nullptr, pool);

    // final
    k_final<<<Gg, HC, 0, stream>>>(pool, cntg, wlin, out);
}

// Round 6
// 549.465 us; speedup vs baseline: 1.4070x; 1.4070x over previous
//
#include <hip/hip_runtime.h>
#include <hip/hip_bf16.h>

// Problem constants
constexpr int Nn  = 20000;
constexpr int Ee  = 320000;
constexpr int Hh  = 6;
constexpr int HC  = 384;   // Hh*64
constexpr int Gg  = 64;
constexpr int NF  = 6;
constexpr int EP  = Ee + Nn;  // edges incl self-loops
constexpr int HW  = HC / 2;   // 192 packed u32 words per node row

typedef __attribute__((ext_vector_type(8))) short short8;
typedef __attribute__((ext_vector_type(4))) float f32x4;

// ---------------- workspace layout (bytes) ----------------
constexpr size_t ALN(size_t x) { return (x + 255) & ~(size_t)255; }
constexpr size_t OFF_H1BF = 0;                                   // N*192 u32 (h1, reused as h2)
constexpr size_t OFF_X2BF = ALN(OFF_H1BF + (size_t)Nn*HW*4);     // N*192 u32
constexpr size_t OFF_ATT  = ALN(OFF_X2BF + (size_t)Nn*HW*4);     // EP*6 f32
constexpr size_t OFF_AS1  = ALN(OFF_ATT  + (size_t)EP*Hh*4);
constexpr size_t OFF_AD1  = ALN(OFF_AS1  + (size_t)Nn*Hh*4);
constexpr size_t OFF_AS2  = ALN(OFF_AD1  + (size_t)Nn*Hh*4);
constexpr size_t OFF_AD2  = ALN(OFF_AS2  + (size_t)Nn*Hh*4);
constexpr size_t OFF_OFFS = ALN(OFF_AD2  + (size_t)Nn*Hh*4);     // (N+1) int
constexpr size_t OFF_ESRC = ALN(OFF_OFFS + (size_t)(Nn+1)*4);
constexpr size_t OFF_EEA  = ALN(OFF_ESRC + (size_t)EP*4);
constexpr size_t OFF_W2BF = ALN(OFF_EEA  + (size_t)EP*4);        // 384*384 bf16
// ---- zeroed block (single memset) ----
constexpr size_t OFF_ZERO = ALN(OFF_W2BF + (size_t)HC*HC*2);
constexpr size_t OFF_CNT  = OFF_ZERO;                            // N int
constexpr size_t OFF_CNT2 = OFF_CNT  + (size_t)Nn*4;             // N int
constexpr size_t OFF_CNTG = OFF_CNT2 + (size_t)Nn*4;             // G int
constexpr size_t OFF_POOL = OFF_CNTG + (size_t)Gg*4;             // G*HC f32
constexpr size_t OFF_SCAL = OFF_POOL + (size_t)Gg*HC*4;          // 64 f32
constexpr size_t ZERO_BYTES = OFF_SCAL + 64*4 - OFF_ZERO;

// ---------------- helpers ----------------
__device__ __forceinline__ float wave_red64(float v) {
    #pragma unroll
    for (int o = 32; o; o >>= 1) v += __shfl_down(v, o);
    return v;
}
__device__ __forceinline__ unsigned short f2bf(float f) {
    union { float f; unsigned u; } v; v.f = f;
    return (unsigned short)((v.u + 0x7fffu + ((v.u >> 16) & 1u)) >> 16);
}
__device__ __forceinline__ unsigned pack2(float a, float b) {
    return (unsigned)f2bf(a) | ((unsigned)f2bf(b) << 16);
}
__device__ __forceinline__ float blo(unsigned w) { union { unsigned u; float f; } v; v.u = w << 16; return v.f; }
__device__ __forceinline__ float bhi(unsigned w) { union { unsigned u; float f; } v; v.u = w & 0xffff0000u; return v.f; }

// -------- mean of edge_attr (sum into scal[0]) --------
__global__ void k_mean(const float* __restrict__ ea, float* __restrict__ scal) {
    int i = blockIdx.x * blockDim.x + threadIdx.x;
    float v = 0.f;
    for (int j = i; j < Ee; j += gridDim.x * blockDim.x) v += ea[j];
    v = wave_red64(v);
    if ((threadIdx.x & 63) == 0) atomicAdd(&scal[0], v);
}

// -------- we_dot[h] for both layers --------
__global__ void k_wedot(const float* __restrict__ we1, const float* __restrict__ atte1,
                        const float* __restrict__ we2, const float* __restrict__ atte2,
                        float* __restrict__ scal) {
    int t = threadIdx.x;  // 384
    float p1 = we1[t] * atte1[t];
    float p2 = we2[t] * atte2[t];
    p1 = wave_red64(p1);
    p2 = wave_red64(p2);
    if ((t & 63) == 0) { int h = t >> 6; scal[1 + h] = p1; scal[7 + h] = p2; }
}

// -------- w2 -> bf16 --------
__global__ void k_cvtw(const float* __restrict__ w2, unsigned short* __restrict__ w2bf) {
    int i = blockIdx.x * blockDim.x + threadIdx.x;
    if (i < HC * HC) w2bf[i] = f2bf(w2[i]);
}

// -------- h1 = x @ W1^T (bf16 packed), attention dots --------
__global__ __launch_bounds__(HW) void k_h1(const float* __restrict__ x, const float* __restrict__ w1,
                                           const float* __restrict__ asrc, const float* __restrict__ adst,
                                           unsigned* __restrict__ h1bf, float* __restrict__ as_, float* __restrict__ ad_) {
    int n = blockIdx.x, t = threadIdx.x;
    int c0 = 2 * t, c1 = c0 + 1;
    float xv[NF];
    #pragma unroll
    for (int k = 0; k < NF; k++) xv[k] = x[n * NF + k];
    float a0 = 0.f, a1 = 0.f;
    #pragma unroll
    for (int k = 0; k < NF; k++) { a0 += xv[k] * w1[c0 * NF + k]; a1 += xv[k] * w1[c1 * NF + k]; }
    h1bf[(size_t)n * HW + t] = pack2(a0, a1);
    float s = a0 * asrc[c0] + a1 * asrc[c1];
    float d = a0 * adst[c0] + a1 * adst[c1];
    #pragma unroll
    for (int o = 16; o; o >>= 1) { s += __shfl_xor(s, o); d += __shfl_xor(d, o); }
    if ((t & 31) == 0) { int h = t >> 5; as_[n * Hh + h] = s; ad_[n * Hh + h] = d; }
}

// -------- CSR build --------
__global__ void k_count(const int* __restrict__ dst, int* __restrict__ cnt) {
    int i = blockIdx.x * blockDim.x + threadIdx.x;
    if (i < EP) {
        int d = (i < Ee) ? dst[i] : (i - Ee);
        atomicAdd(&cnt[d], 1);
    }
}

__global__ __launch_bounds__(1024) void k_scan(const int* __restrict__ cnt, int* __restrict__ offs) {
    __shared__ int wsum[16];
    __shared__ int carry_s;
    int t = threadIdx.x, lane = t & 63, wid = t >> 6;
    if (t == 0) carry_s = 0;
    __syncthreads();
    for (int base = 0; base < Nn; base += 1024) {
        int idx = base + t;
        int v = (idx < Nn) ? cnt[idx] : 0;
        int x = v;
        #pragma unroll
        for (int o = 1; o < 64; o <<= 1) { int y = __shfl_up(x, o); if (lane >= o) x += y; }
        if (lane == 63) wsum[wid] = x;
        __syncthreads();
        int wbase = 0;
        for (int i = 0; i < wid; i++) wbase += wsum[i];
        int excl = carry_s + wbase + x - v;
        if (idx < Nn) offs[idx] = excl;
        __syncthreads();
        if (t == 1023) carry_s = excl + v;
        __syncthreads();
    }
    if (t == 0) offs[Nn] = carry_s;
}

__global__ void k_scatter(const int* __restrict__ src, const int* __restrict__ dst,
                          const float* __restrict__ ea, const int* __restrict__ offs,
                          int* __restrict__ cnt2, int* __restrict__ esrc, float* __restrict__ eea,
                          const float* __restrict__ scal) {
    int i = blockIdx.x * blockDim.x + threadIdx.x;
    if (i >= EP) return;
    int d, s; float a;
    if (i < Ee) { d = dst[i]; s = src[i]; a = ea[i]; }
    else        { d = i - Ee; s = d; a = scal[0] * (1.0f / Ee); }
    int p = offs[d] + atomicAdd(&cnt2[d], 1);
    esrc[p] = s;
    eea[p]  = a;
}

// -------- per-(node,head) softmax: materialize att[e,h] --------
template <int LAYER>
__global__ void k_att(const float* __restrict__ as_, const float* __restrict__ ad_,
                      const int* __restrict__ offs, const int* __restrict__ esrc,
                      const float* __restrict__ eea, const float* __restrict__ scal,
                      float* __restrict__ att) {
    int idx = blockIdx.x * blockDim.x + threadIdx.x;
    if (idx >= Nn * Hh) return;
    int n = idx / Hh, h = idx - n * Hh;
    int s0 = offs[n], s1 = offs[n + 1];
    float adn = ad_[idx];
    float wdh = scal[(LAYER == 1 ? 1 : 7) + h];
    float m = -3.4e38f, den = 0.f;
    for (int j = s0; j < s1; ++j) {
        int s = esrc[j]; float a = eea[j];
        float al = as_[s * Hh + h] + adn + a * wdh;
        al = (al > 0.f) ? al : 0.2f * al;
        float mn = fmaxf(m, al);
        den = den * __expf(m - mn) + __expf(al - mn);
        m = mn;
    }
    float rden = 1.f / den;
    for (int j = s0; j < s1; ++j) {
        int s = esrc[j]; float a = eea[j];
        float al = as_[s * Hh + h] + adn + a * wdh;
        al = (al > 0.f) ? al : 0.2f * al;
        att[j * Hh + h] = __expf(al - m) * rden;
    }
}

// -------- aggregation: pure gather-weighted sum (bf16 rows), bias+ELU fused --------
template <int LAYER>
__global__ __launch_bounds__(HW) void k_agg(const unsigned* __restrict__ hbf, const float* __restrict__ att,
                                            const int* __restrict__ offs, const int* __restrict__ esrc,
                                            const float* __restrict__ bias, const int* __restrict__ batch,
                                            unsigned* __restrict__ xout, float* __restrict__ pool) {
    int n = blockIdx.x, t = threadIdx.x, h = t >> 5;
    int s0 = offs[n], s1 = offs[n + 1];
    float ax = 0.f, ay = 0.f;
    unsigned wA = 0; float aA = 0.f;
    int sB = 0;
    if (s0 < s1) {
        int sA = esrc[s0];
        wA = hbf[(size_t)sA * HW + t];
        aA = att[s0 * Hh + h];
        if (s0 + 1 < s1) sB = esrc[s0 + 1];
    }
    for (int j = s0; j < s1; ++j) {
        unsigned wB = 0; float aB = 0.f;
        int sC = sB;
        if (j + 2 < s1) sC = esrc[j + 2];
        if (j + 1 < s1) { wB = hbf[(size_t)sB * HW + t]; aB = att[(j + 1) * Hh + h]; }
        ax += aA * blo(wA);
        ay += aA * bhi(wA);
        wA = wB; aA = aB; sB = sC;
    }
    float o0 = ax + bias[2 * t], o1 = ay + bias[2 * t + 1];
    o0 = (o0 > 0.f) ? o0 : (__expf(o0) - 1.f);
    o1 = (o1 > 0.f) ? o1 : (__expf(o1) - 1.f);
    if (LAYER == 1) {
        xout[(size_t)n * HW + t] = pack2(o0, o1);
    } else {
        float* pp = pool + batch[n] * HC + 2 * t;
        atomicAdd(pp, o0);
        atomicAdd(pp + 1, o1);
    }
}

// -------- MFMA GEMM: h2 = x2 @ w2^T, bf16 in, bf16 out --------
__global__ __launch_bounds__(256) void k_gemm(const unsigned short* __restrict__ x2bf,
                                              const unsigned short* __restrict__ w2bf,
                                              unsigned short* __restrict__ h2bf) {
    int t = threadIdx.x, l = t & 63, w = t >> 6;
    int m0 = blockIdx.x * 32;
    int n0 = w * 96;
    int lr = l & 15, lk = l >> 4;
    f32x4 acc[2][6];
    #pragma unroll
    for (int mi = 0; mi < 2; mi++)
        #pragma unroll
        for (int f = 0; f < 6; f++) acc[mi][f] = (f32x4){0.f, 0.f, 0.f, 0.f};
    int mrow0 = m0 + lr, mrow1 = m0 + 16 + lr;
    int r0 = mrow0 < Nn ? mrow0 : Nn - 1;
    int r1 = mrow1 < Nn ? mrow1 : Nn - 1;
    for (int ks = 0; ks < HC / 32; ks++) {
        int koff = ks * 32 + lk * 8;
        short8 a0 = *(const short8*)(x2bf + (size_t)r0 * HC + koff);
        short8 a1 = *(const short8*)(x2bf + (size_t)r1 * HC + koff);
        #pragma unroll
        for (int f = 0; f < 6; f++) {
            short8 b = *(const short8*)(w2bf + (size_t)(n0 + f * 16 + lr) * HC + koff);
            acc[0][f] = __builtin_amdgcn_mfma_f32_16x16x32_bf16(a0, b, acc[0][f], 0, 0, 0);
            acc[1][f] = __builtin_amdgcn_mfma_f32_16x16x32_bf16(a1, b, acc[1][f], 0, 0, 0);
        }
    }
    #pragma unroll
    for (int mi = 0; mi < 2; mi++) {
        int rowb = m0 + mi * 16 + lk * 4;
        #pragma unroll
        for (int r = 0; r < 4; r++) {
            int row = rowb + r;
            if (row < Nn) {
                unsigned short* dp = h2bf + (size_t)row * HC + n0 + lr;
                #pragma unroll
                for (int f = 0; f < 6; f++) dp[f * 16] = f2bf(acc[mi][f][r]);
            }
        }
    }
}

// -------- attention dots for layer 2 (bf16 h2) --------
__global__ __launch_bounds__(HW) void k_attn2(const unsigned* __restrict__ h2bf, const float* __restrict__ asrc,
                                              const float* __restrict__ adst,
                                              float* __restrict__ as_, float* __restrict__ ad_) {
    int n = blockIdx.x, t = threadIdx.x;
    unsigned w = h2bf[(size_t)n * HW + t];
    float v0 = blo(w), v1 = bhi(w);
    float s = v0 * asrc[2 * t] + v1 * asrc[2 * t + 1];
    float d = v0 * adst[2 * t] + v1 * adst[2 * t + 1];
    #pragma unroll
    for (int o = 16; o; o >>= 1) { s += __shfl_xor(s, o); d += __shfl_xor(d, o); }
    if ((t & 31) == 0) { int h = t >> 5; as_[n * Hh + h] = s; ad_[n * Hh + h] = d; }
}

__global__ void k_cntg(const int* __restrict__ batch, int* __restrict__ cntg) {
    int i = blockIdx.x * blockDim.x + threadIdx.x;
    if (i < Nn) atomicAdd(&cntg[batch[i]], 1);
}

// -------- final: mean pool -> linear -> sigmoid --------
__global__ __launch_bounds__(HC) void k_final(const float* __restrict__ pool, const int* __restrict__ cntg,
                                              const float* __restrict__ wlin, float* __restrict__ out) {
    __shared__ float partial[Hh];
    int g = blockIdx.x, t = threadIdx.x;
    float v = pool[g * HC + t] * wlin[t];
    v = wave_red64(v);
    if ((t & 63) == 0) partial[t >> 6] = v;
    __syncthreads();
    if (t == 0) {
        float s = 0.f;
        #pragma unroll
        for (int h = 0; h < Hh; h++) s += partial[h];
        int c = cntg[g];
        float denom = (float)(c > 1 ? c : 1);
        out[g] = 1.f / (1.f + __expf(-s / denom));
    }
}

extern "C" void kernel_launch(void* const* d_in, const int* in_sizes, int n_in,
                              void* d_out, int out_size, void* d_ws, size_t ws_size,
                              hipStream_t stream) {
    const float* x        = (const float*)d_in[0];
    const float* ea       = (const float*)d_in[1];
    const int*   eidx     = (const int*)d_in[2];
    const int*   batch    = (const int*)d_in[3];
    const float* w1       = (const float*)d_in[4];
    const float* att_src1 = (const float*)d_in[5];
    const float* att_dst1 = (const float*)d_in[6];
    const float* we1      = (const float*)d_in[7];
    const float* atte1    = (const float*)d_in[8];
    const float* b1       = (const float*)d_in[9];
    const float* w2       = (const float*)d_in[10];
    const float* att_src2 = (const float*)d_in[11];
    const float* att_dst2 = (const float*)d_in[12];
    const float* we2      = (const float*)d_in[13];
    const float* atte2    = (const float*)d_in[14];
    const float* b2       = (const float*)d_in[15];
    const float* wlin     = (const float*)d_in[16];
    float* out = (float*)d_out;

    char* ws = (char*)d_ws;
    unsigned* h1bf = (unsigned*)(ws + OFF_H1BF);     // also h2bf
    unsigned* x2bf = (unsigned*)(ws + OFF_X2BF);
    float* att  = (float*)(ws + OFF_ATT);
    float* as1  = (float*)(ws + OFF_AS1);
    float* ad1  = (float*)(ws + OFF_AD1);
    float* as2  = (float*)(ws + OFF_AS2);
    float* ad2  = (float*)(ws + OFF_AD2);
    int*   offs = (int*)(ws + OFF_OFFS);
    int*   esrc = (int*)(ws + OFF_ESRC);
    float* eea  = (float*)(ws + OFF_EEA);
    unsigned short* w2bf = (unsigned short*)(ws + OFF_W2BF);
    int*   cnt  = (int*)(ws + OFF_CNT);
    int*   cnt2 = (int*)(ws + OFF_CNT2);
    int*   cntg = (int*)(ws + OFF_CNTG);
    float* pool = (float*)(ws + OFF_POOL);
    float* scal = (float*)(ws + OFF_SCAL);

    const int* src = eidx;
    const int* dst = eidx + Ee;

    hipMemsetAsync(ws + OFF_ZERO, 0, ZERO_BYTES, stream);

    k_mean<<<256, 256, 0, stream>>>(ea, scal);
    k_wedot<<<1, HC, 0, stream>>>(we1, atte1, we2, atte2, scal);
    k_cvtw<<<(HC * HC + 255) / 256, 256, 0, stream>>>(w2, w2bf);

    k_h1<<<Nn, HW, 0, stream>>>(x, w1, att_src1, att_dst1, h1bf, as1, ad1);

    int ecb = (EP + 255) / 256;
    k_count<<<ecb, 256, 0, stream>>>(dst, cnt);
    k_scan<<<1, 1024, 0, stream>>>(cnt, offs);
    k_scatter<<<ecb, 256, 0, stream>>>(src, dst, ea, offs, cnt2, esrc, eea, scal);

    int nhb = (Nn * Hh + 255) / 256;
    k_att<1><<<nhb, 256, 0, stream>>>(as1, ad1, offs, esrc, eea, scal, att);
    k_agg<1><<<Nn, HW, 0, stream>>>(h1bf, att, offs, esrc, b1, nullptr, x2bf, nullptr);

    k_gemm<<<(Nn + 31) / 32, 256, 0, stream>>>((const unsigned short*)x2bf, w2bf, (unsigned short*)h1bf);
    k_attn2<<<Nn, HW, 0, stream>>>(h1bf, att_src2, att_dst2, as2, ad2);

    k_cntg<<<(Nn + 255) / 256, 256, 0, stream>>>(batch, cntg);

    k_att<2><<<nhb, 256, 0, stream>>>(as2, ad2, offs, esrc, eea, scal, att);
    k_agg<2><<<Nn, HW, 0, stream>>>(h1bf, att, offs, esrc, b2, batch, nullptr, pool);

    k_final<<<Gg, HC, 0, stream>>>(pool, cntg, wlin, out);
}